// Round 21
// baseline (459.187 us; speedup 1.0000x reference)
//
#include <hip/hip_runtime.h>

// DeepCNF: 5x conv1d(K=11)+tanh -> 1x1 conv to 8 tags -> CRF NLL (sum over batch).
// B=128 T=1024 IN=42 HID=256 K=11 NTAGS=8.
// All conv layers now fp8 e4m3 with MX-scaled K=128 MFMA (scales=1.0).
// conv_first: 6 iterations (tap pairs (0,1)..(10,11), tap 11 zero-padded in
// the weight table); input staged fp8 in LDS with 80B row stride (2-way bank
// aliasing = free), 139 rows staged so the tap-11 read never hits
// uninitialized LDS (e4m3 0xFF would be NaN).
// conv_mid: r19 structure (best measured 453.8us): 128t x 64co wave tile,
// single A buffer, B 2-slot rotation, (256,2). At ~1.55 PF it matches the
// structural ceiling of this loop class (m148: 1628 TF) -- further gains
// need the 8-phase template, not micro-pipelining (r14-r20 evidence).
// Weights pre-scaled x256 (e4m3 subnormal avoidance), epilogue x1/256.
// H (fp8): row = (b*T+t)*256 bytes, 16B chunks stored at (chunk ^ (t&15)).
// conv4 fuses the emission projection via LDS partial reduce (no atomics).
// CRF: log-semiring segment matrix products (32 segments of 32 steps).

#define B_ 128
#define T_ 1024
#define IN_DIM_ 42
#define HID_ 256
#define KW_ 11
#define NTAGS_ 8
#define SEG_ 32
#define SEGL_ (T_ / SEG_)   // 32

typedef float f32x4 __attribute__((ext_vector_type(4)));
typedef int i32x4 __attribute__((ext_vector_type(4)));
typedef int i32x8 __attribute__((ext_vector_type(8)));

struct i4pair { i32x4 lo, hi; };
__device__ __forceinline__ i32x8 mk8(i32x4 lo, i32x4 hi) {
    i4pair p{lo, hi};
    return __builtin_bit_cast(i32x8, p);
}

__device__ __forceinline__ float fast_tanh(float x) {
    float e = __expf(2.f * x);          // inf/0 saturate to +-1 correctly
    return 1.f - 2.f / (e + 1.f);
}
__device__ __forceinline__ unsigned char f2fp8(float v) {
    return (unsigned char)(__builtin_amdgcn_cvt_pk_fp8_f32(v, v, 0, false) & 0xff);
}

#define SZ0F8_ (6 * 16 * 64 * 32)       // layer0 fp8 K128 table = 196608 B
#define SZF8_  (22 * 16 * 64 * 32)      // per mid layer fp8 K128 table = 720896 B

// ---------------------------------------------------------------------------
// Pack layer-0 weights fp32 -> fp8 e4m3 (x256), K=128 frags over tap pairs:
// it=0..5, kq=(l>>4)*32+e, tap=2*it+(kq>>6), c=kq&63 (zero for tap 11, c>=42)
// wp[((it*16+coc)*64+lane)*32+e] = fp8(256*w0[(co*42+c)*11+tap])
// ---------------------------------------------------------------------------
__global__ void pack_l0f8(const float* __restrict__ w0, unsigned char* __restrict__ wp) {
    for (int idx = blockIdx.x * 256 + threadIdx.x; idx < SZ0F8_;
         idx += gridDim.x * 256) {
        int e    = idx & 31;
        int lane = (idx >> 5) & 63;
        int coc  = (idx >> 11) & 15;
        int it   = idx >> 15;          // 0..5
        int kq   = (lane >> 4) * 32 + e;
        int tap  = 2 * it + (kq >> 6);
        int c    = kq & 63;
        int co   = coc * 16 + (lane & 15);
        float v = (tap < KW_ && c < IN_DIM_)
                      ? 256.f * w0[(co * IN_DIM_ + c) * KW_ + tap] : 0.f;
        wp[idx] = f2fp8(v);
    }
}

// ---------------------------------------------------------------------------
// Pack mid weights fp32 -> fp8 e4m3 (x256), K=128 B-frags, it = cic128*11+k:
// wp8[((it*16+coc)*64+lane)*32+e] =
//   fp8(256 * w[coc*16+(l&15)][cic128*128+(l>>4)*32+e][k])
// ---------------------------------------------------------------------------
__global__ void pack_f8(const float* __restrict__ w1, const float* __restrict__ w2,
                        const float* __restrict__ w3, const float* __restrict__ w4,
                        unsigned char* __restrict__ wp8) {
    const int total = 4 * SZF8_;
    for (int idx = blockIdx.x * 256 + threadIdx.x; idx < total;
         idx += gridDim.x * 256) {
        int L   = idx / SZF8_;
        int loc = idx - L * SZF8_;
        const float* w = (L == 0) ? w1 : (L == 1) ? w2 : (L == 2) ? w3 : w4;
        int e    = loc & 31;
        int lane = (loc >> 5) & 63;
        int coc  = (loc >> 11) & 15;
        int it   = loc >> 15;          // 0..21
        int cic  = it / KW_;
        int k    = it - cic * KW_;
        int co = coc * 16 + (lane & 15);
        int ci = cic * 128 + (lane >> 4) * 32 + e;
        wp8[idx] = f2fp8(256.f * w[(co * HID_ + ci) * KW_ + k]);
    }
}

// ---------------------------------------------------------------------------
// First conv layer (fp8 K=128): 128t x 256co block, 8 waves (2 wr x 4 wc),
// wave tile 64t x 64co, 6 iterations of 16 MFMA. Input fp32 -> fp8 staged in
// LDS [139][80B] (64ch padded, rows 80B stride). Tap-11 A reads hit staged
// (zeroed) rows; tap-11 weights are zero. Output fp8 H (t&15 chunk swizzle).
// ---------------------------------------------------------------------------
__global__ __launch_bounds__(512, 4)
void conv_first(const float* __restrict__ x, const unsigned char* __restrict__ wpack,
                const float* __restrict__ bias, unsigned char* __restrict__ out) {
    __shared__ unsigned char lds8[139 * 80];

    const int tid  = threadIdx.x;
    const int wave = tid >> 6;
    const int lane = tid & 63;
    const int l15  = lane & 15;
    const int lhi  = lane >> 4;
    const int wr   = wave >> 2;
    const int wc   = wave & 3;
    const int b    = blockIdx.x >> 3;
    const int t0   = (blockIdx.x & 7) * 128;

    // stage rows [t0-5, t0+134) as fp8, 64ch (zeros for c>=42 / out-of-range)
    for (int u = tid; u < 139 * 16; u += 512) {
        int r = u >> 4, q = u & 15;
        int gt = t0 - 5 + r;
        unsigned pk = 0;
        if (gt >= 0 && gt < T_) {
            const float* xr = &x[((size_t)b * T_ + gt) * IN_DIM_];
#pragma unroll
            for (int j = 0; j < 4; ++j) {
                int c = q * 4 + j;
                if (c < IN_DIM_) pk |= (unsigned)f2fp8(xr[c]) << (8 * j);
            }
        }
        *(unsigned*)&lds8[r * 80 + q * 4] = pk;
    }
    __syncthreads();

    f32x4 acc[4][4];
#pragma unroll
    for (int tf = 0; tf < 4; ++tf)
#pragma unroll
        for (int n = 0; n < 4; ++n) acc[tf][n] = (f32x4){0.f, 0.f, 0.f, 0.f};

    const unsigned char* wpB = wpack + (size_t)(wc * 4) * 2048 + lane * 32;
    // A row = wr*64 + tf*16 + l15 + 2*it + (lhi>>1); byte = row*80 + (lhi&1)*32
    const int abase0 = (wr * 64 + l15 + (lhi >> 1)) * 80 + (lhi & 1) * 32;

    i32x8 Aa[4], Bs0, Bs1;

#define LOAD_BS(SLOT, itv, nv)                                                 \
    {                                                                          \
        const unsigned char* p_ = wpB + (size_t)(itv) * 32768 + (nv) * 2048;   \
        SLOT = mk8(*(const i32x4*)p_, *(const i32x4*)(p_ + 16));               \
    }
#define CL(BS, n_)                                                             \
    {                                                                          \
        __builtin_amdgcn_s_setprio(1);                                         \
        _Pragma("unroll") for (int tf = 0; tf < 4; ++tf)                       \
            acc[tf][n_] = __builtin_amdgcn_mfma_scale_f32_16x16x128_f8f6f4(    \
                Aa[tf], BS, acc[tf][n_], 0, 0,                                 \
                0, 0x7F7F7F7F, 0, 0x7F7F7F7F);   /* scales = 1.0 */            \
        __builtin_amdgcn_s_setprio(0);                                         \
    }

    LOAD_BS(Bs0, 0, 0);
    LOAD_BS(Bs1, 0, 1);

#pragma unroll
    for (int it = 0; it < 6; ++it) {
        const int ab = abase0 + it * 160;
#pragma unroll
        for (int tf = 0; tf < 4; ++tf)
            Aa[tf] = mk8(*(const i32x4*)&lds8[ab + tf * 1280],
                         *(const i32x4*)&lds8[ab + tf * 1280 + 16]);
        CL(Bs0, 0); LOAD_BS(Bs0, it, 2);
        CL(Bs1, 1); LOAD_BS(Bs1, it, 3);
        CL(Bs0, 2); LOAD_BS(Bs0, it + 1, 0);   // it=5 -> overrun into mid
        CL(Bs1, 3); LOAD_BS(Bs1, it + 1, 1);   //   table (benign reads)
    }
#undef LOAD_BS
#undef CL

    constexpr float INV = 1.f / 256.f;   // undo weight scale
    // epilogue: bias + tanh -> fp8, stored 16B-chunk-swizzled by (t&15)
#pragma unroll
    for (int n = 0; n < 4; ++n) {
        int co = wc * 64 + n * 16 + l15;
        float bv = bias[co];
        int cch = co >> 4, cby = co & 15;
#pragma unroll
        for (int tf = 0; tf < 4; ++tf) {
#pragma unroll
            for (int r4 = 0; r4 < 4; ++r4) {
                int t = t0 + wr * 64 + tf * 16 + lhi * 4 + r4;
                float v = fast_tanh(acc[tf][n][r4] * INV + bv);
                out[((size_t)b * T_ + t) * 256 + ((cch ^ (t & 15)) << 4) + cby] =
                    f2fp8(v);
            }
        }
    }
}

// ---------------------------------------------------------------------------
// Mid conv (fp8, K=128 scaled MFMA): 128t x 256co block, 4 waves, wave tile
// 128t x 64co (acc[8][4]), 22 rolled iterations of 32 MFMA. Single A buffer
// (16x ds_read_b128) + B 2-slot rotation. launch_bounds(256,2), 35KB LDS,
// 2 blocks/CU. All register indices static (rule #20 safe). [r19 structure]
// LAST: fused emission projection via LDS partial reduce (no atomics).
// ---------------------------------------------------------------------------
template <bool LAST>
__global__ __launch_bounds__(256, 2)
void conv_mid(const unsigned char* __restrict__ Hin,
              const unsigned char* __restrict__ wpack,
              const float* __restrict__ bias, unsigned char* __restrict__ out,
              const float* __restrict__ w_out, float* __restrict__ emout) {
    extern __shared__ unsigned char lds8[];   // [140][256] = 35840 B (138 used)

    const int tid  = threadIdx.x;
    const int wave = tid >> 6;
    const int lane = tid & 63;
    const int l15  = lane & 15;
    const int lhi  = lane >> 4;
    const int wc   = wave;                    // co-quarter
    const int b    = blockIdx.x >> 3;
    const int t0   = (blockIdx.x & 7) * 128;

    // ---- stage rows [t0-5, t0+133) as verbatim 256B rows (swizzle carried) --
    for (int c = wave; c < 35; c += 4) {
        int r0 = c * 4;
        int r  = r0 + (lane >> 4);
        int gt = t0 - 5 + r;
        gt = gt < 0 ? 0 : (gt >= T_ ? T_ - 1 : gt);   // clamp; zeroed below
        const unsigned char* src =
            Hin + ((size_t)b * T_ + gt) * 256 + (lane & 15) * 16;
        __builtin_amdgcn_global_load_lds(
            (const __attribute__((address_space(1))) void*)src,
            (__attribute__((address_space(3))) void*)&lds8[r0 * 256], 16, 0, 0);
    }
    __syncthreads();
    if (t0 == 0) {
        for (int u = tid; u < 320; u += 256)
            ((unsigned*)lds8)[u] = 0;                  // rows 0..4
    }
    if (t0 == T_ - 128) {
        for (int u = tid; u < 320; u += 256)
            ((unsigned*)&lds8[133 * 256])[u] = 0;      // rows 133..137
    }
    __syncthreads();

    f32x4 acc[8][4];
#pragma unroll
    for (int tf = 0; tf < 8; ++tf)
#pragma unroll
        for (int n = 0; n < 4; ++n) acc[tf][n] = (f32x4){0.f, 0.f, 0.f, 0.f};

    const unsigned char* wpB = wpack + (size_t)(wc * 4) * 2048 + lane * 32;

    i32x8 Aa[8], Bs0, Bs1;

    // B frag (itv, nv): 32B at wpB + itv*32768 + nv*2048
#define LOAD_BS(SLOT, itv, nv)                                                 \
    {                                                                          \
        const unsigned char* p_ = wpB + (size_t)(itv) * 32768 + (nv) * 2048;   \
        SLOT = mk8(*(const i32x4*)p_, *(const i32x4*)(p_ + 16));               \
    }
    // one 8-MFMA cluster: column n_ against B slot BS
#define CL(BS, n_)                                                             \
    {                                                                          \
        __builtin_amdgcn_s_setprio(1);                                         \
        _Pragma("unroll") for (int tf = 0; tf < 8; ++tf)                       \
            acc[tf][n_] = __builtin_amdgcn_mfma_scale_f32_16x16x128_f8f6f4(    \
                Aa[tf], BS, acc[tf][n_], 0, 0,                                 \
                0, 0x7F7F7F7F, 0, 0x7F7F7F7F);   /* scales = 1.0 */            \
        __builtin_amdgcn_s_setprio(0);                                         \
    }

    LOAD_BS(Bs0, 0, 0);
    LOAD_BS(Bs1, 0, 1);

    // Rolled runtime K-loop: all register indices static (rule #20 safe).
#pragma unroll 1
    for (int kk = 0; kk < 22; ++kk) {
        // A frag addresses for iteration kk: lane covers
        // ci = cic*128 + lhi*32 + [0,32), row = tf*16 + l15 + k (tf 0..7).
        // Chunks c0 = cic*8+lhi*2 and c0+1, stored at (c ^ key),
        // key = (l15+k+11)&15 -> second read is addr ^ 16.
        const int cic_ = kk / KW_;            // uniform: magic-mul, cheap
        const int kn_  = kk - cic_ * KW_;
        const int key_ = (l15 + kn_ + 11) & 15;
        const int ca_  = ((cic_ * 8 + lhi * 2) ^ key_) << 4;
        const int rb_  = (l15 + kn_) * 256 + ca_;
#pragma unroll
        for (int tf = 0; tf < 8; ++tf)
            Aa[tf] = mk8(*(const i32x4*)&lds8[rb_ + tf * 4096],
                         *(const i32x4*)&lds8[(rb_ + tf * 4096) ^ 16]);
        CL(Bs0, 0); LOAD_BS(Bs0, kk, 2);
        CL(Bs1, 1); LOAD_BS(Bs1, kk, 3);
        CL(Bs0, 2); LOAD_BS(Bs0, kk + 1, 0);   // kk=21 -> it 22: overrun
        CL(Bs1, 3); LOAD_BS(Bs1, kk + 1, 1);   // into next table (benign)
    }
#undef LOAD_BS
#undef CL

    constexpr float INV = 1.f / 256.f;   // undo weight scale
    if constexpr (!LAST) {
        // epilogue: bias + tanh -> fp8 H, 16B-chunk swizzle by (t&15)
#pragma unroll
        for (int n = 0; n < 4; ++n) {
            int co = wc * 64 + n * 16 + l15;
            float bv = bias[co];
            int cch = co >> 4, cby = co & 15;
#pragma unroll
            for (int tf = 0; tf < 8; ++tf) {
#pragma unroll
                for (int r4 = 0; r4 < 4; ++r4) {
                    int t = t0 + tf * 16 + lhi * 4 + r4;
                    float v = fast_tanh(acc[tf][n][r4] * INV + bv);
                    out[((size_t)b * T_ + t) * 256 + ((cch ^ (t & 15)) << 4) + cby] =
                        f2fp8(v);
                }
            }
        }
    } else {
        // fused emissions: wave partial over its 64 co -> LDS -> reduce over wc
        float wv[4][NTAGS_], bvn[4];
#pragma unroll
        for (int n = 0; n < 4; ++n) {
            int co = wc * 64 + n * 16 + l15;
            bvn[n] = bias[co];
#pragma unroll
            for (int tg = 0; tg < NTAGS_; ++tg) wv[n][tg] = w_out[tg * HID_ + co];
        }
        __syncthreads();                 // A-tile reads done; reuse LDS
        float* pbuf = (float*)lds8;      // [4 wc][128 t][8 tg] = 16 KB
#pragma unroll
        for (int tf = 0; tf < 8; ++tf) {
#pragma unroll
            for (int r4 = 0; r4 < 4; ++r4) {
                float h[4];
#pragma unroll
                for (int n = 0; n < 4; ++n)
                    h[n] = fast_tanh(acc[tf][n][r4] * INV + bvn[n]);
                float pt[NTAGS_];
#pragma unroll
                for (int tg = 0; tg < NTAGS_; ++tg)
                    pt[tg] = h[0] * wv[0][tg] + h[1] * wv[1][tg] +
                             h[2] * wv[2][tg] + h[3] * wv[3][tg];
#pragma unroll
                for (int off = 8; off; off >>= 1)
#pragma unroll
                    for (int tg = 0; tg < NTAGS_; ++tg)
                        pt[tg] += __shfl_down(pt[tg], off);
                if (l15 == 0) {
                    int tloc = tf * 16 + lhi * 4 + r4;
                    f32x4 lo = {pt[0], pt[1], pt[2], pt[3]};
                    f32x4 hi = {pt[4], pt[5], pt[6], pt[7]};
                    *(f32x4*)&pbuf[(wc * 128 + tloc) * 8]     = lo;
                    *(f32x4*)&pbuf[(wc * 128 + tloc) * 8 + 4] = hi;
                }
            }
        }
        __syncthreads();
        for (int u = tid; u < 128 * NTAGS_; u += 256) {
            float s = pbuf[u] + pbuf[1024 + u] + pbuf[2048 + u] + pbuf[3072 + u];
            emout[((size_t)b * T_ + t0) * NTAGS_ + u] = s;
        }
    }
}

// ---------------------------------------------------------------------------
// CRF segment kernel: wave per (b, s). Lane (i=lane>>3, j=lane&7) holds
// M[i][j], lse-product of S_t[i][j] = tr[i][j] + em[b,t,j] + bo[j].
// ---------------------------------------------------------------------------
__global__ __launch_bounds__(256)
void crf_seg_kernel(const float* __restrict__ em, const float* __restrict__ tr,
                    const float* __restrict__ bo, float* __restrict__ segM) {
    const int gw   = blockIdx.x * 4 + (threadIdx.x >> 6);
    const int b    = gw >> 5;
    const int s    = gw & 31;
    const int lane = threadIdx.x & 63;
    const int i    = lane >> 3;
    const int j    = lane & 7;
    const float* emb = em + (size_t)b * T_ * NTAGS_;
    const float boj = bo[j];

    float tc[8];
#pragma unroll
    for (int k = 0; k < 8; ++k) tc[k] = tr[k * 8 + j];

    const int tb = (s == 0) ? 1 : s * SEGL_;
    const int te = (s + 1) * SEGL_;

    float m = tr[i * 8 + j] + emb[tb * 8 + j] + boj;
    for (int t = tb + 1; t < te; ++t) {
        float emt = emb[t * 8 + j] + boj;
        float v[8];
#pragma unroll
        for (int k = 0; k < 8; ++k) v[k] = __shfl(m, (lane & 56) + k) + tc[k];
        float mx = fmaxf(fmaxf(fmaxf(v[0], v[1]), fmaxf(v[2], v[3])),
                         fmaxf(fmaxf(v[4], v[5]), fmaxf(v[6], v[7])));
        float sm = 0.f;
#pragma unroll
        for (int k = 0; k < 8; ++k) sm += __expf(v[k] - mx);
        m = mx + __logf(sm) + emt;
    }
    segM[(size_t)gw * 64 + lane] = m;
}

// ---------------------------------------------------------------------------
// CRF combine: one wave per batch. Numerator + 32-segment fold.
// ---------------------------------------------------------------------------
__global__ __launch_bounds__(64)
void crf_kernel(const float* __restrict__ em, const float* __restrict__ segM,
                const int* __restrict__ tags,
                const float* __restrict__ st, const float* __restrict__ et,
                const float* __restrict__ tr, const float* __restrict__ bo,
                float* __restrict__ outp) {
    __shared__ float sM[SEG_ * 64];
    const int b    = blockIdx.x;
    const int lane = threadIdx.x;
    const float* emb = em + (size_t)b * T_ * NTAGS_;
    const int*   tg  = tags + (size_t)b * T_;

    for (int u = lane; u < SEG_ * 64; u += 64)
        sM[u] = segM[(size_t)b * SEG_ * 64 + u];

    const float breg = bo[lane & 7];

    float num = 0.f;
    for (int t = 1 + lane; t < T_; t += 64) {
        int pt = tg[t - 1], ct = tg[t];
        num += tr[pt * NTAGS_ + ct] + emb[t * NTAGS_ + ct] + __shfl(breg, ct);
    }
#pragma unroll
    for (int off = 32; off; off >>= 1) num += __shfl_down(num, off);
    int tgf = tg[0], tgl = tg[T_ - 1];
    float bo_f = __shfl(breg, tgf);
    float score = 0.f;
    if (lane == 0)
        score = num + st[tgf] + emb[tgf] + bo_f + et[tgl];

    __syncthreads();

    const int j = lane & 7;
    float alpha = st[j] + emb[j] + breg;
    for (int sgm = 0; sgm < SEG_; ++sgm) {
        const float* M = &sM[sgm * 64];
        float v[8];
#pragma unroll
        for (int i = 0; i < 8; ++i) v[i] = __shfl(alpha, i) + M[i * 8 + j];
        float mx = fmaxf(fmaxf(fmaxf(v[0], v[1]), fmaxf(v[2], v[3])),
                         fmaxf(fmaxf(v[4], v[5]), fmaxf(v[6], v[7])));
        float sm = 0.f;
#pragma unroll
        for (int i = 0; i < 8; ++i) sm += __expf(v[i] - mx);
        alpha = mx + __logf(sm);
    }
    float vj = alpha + et[j];
    float w[8];
#pragma unroll
    for (int i = 0; i < 8; ++i) w[i] = __shfl(vj, i);
    float m2 = w[0];
#pragma unroll
    for (int i = 1; i < 8; ++i) m2 = fmaxf(m2, w[i]);
    float s2 = 0.f;
#pragma unroll
    for (int i = 0; i < 8; ++i) s2 += __expf(w[i] - m2);
    float log_z = m2 + __logf(s2);

    if (lane == 0) atomicAdd(outp, log_z - score);
}

// ---------------------------------------------------------------------------
extern "C" void kernel_launch(void* const* d_in, const int* in_sizes, int n_in,
                              void* d_out, int out_size, void* d_ws, size_t ws_size,
                              hipStream_t stream) {
    const float* x     = (const float*)d_in[0];
    const int*   tags  = (const int*)d_in[3];
    const float* w[5]  = {(const float*)d_in[4], (const float*)d_in[6],
                          (const float*)d_in[8], (const float*)d_in[10],
                          (const float*)d_in[12]};
    const float* bias[5] = {(const float*)d_in[5], (const float*)d_in[7],
                            (const float*)d_in[9], (const float*)d_in[11],
                            (const float*)d_in[13]};
    const float* w_out = (const float*)d_in[14];
    const float* b_out = (const float*)d_in[15];
    const float* st    = (const float*)d_in[16];
    const float* et    = (const float*)d_in[17];
    const float* tr    = (const float*)d_in[18];

    // workspace: H0, H1 (fp8), wp0f8, wpf8 x4, em, segM
    unsigned char* H0 = (unsigned char*)d_ws;
    unsigned char* H1 = H0 + (size_t)B_ * T_ * 256;
    unsigned char* wp0 = H1 + (size_t)B_ * T_ * 256;
    unsigned char* wpf8 = wp0 + SZ0F8_;
    float* em   = (float*)(wpf8 + 4 * (size_t)SZF8_);
    float* segM = em + (size_t)B_ * T_ * NTAGS_;
    // B-prefetch overruns a table by <=1 it-group (32KB): wp0 -> wpf8, wpf8
    // layers into each other, last layer into em (reads only, never consumed).

    pack_l0f8<<<768, 256, 0, stream>>>(w[0], wp0);
    pack_f8<<<2048, 256, 0, stream>>>(w[1], w[2], w[3], w[4], wpf8);

    conv_first<<<B_ * (T_ / 128), 512, 0, stream>>>(x, wp0, bias[0], H0);

    const int NBLK = B_ * (T_ / 128);  // 1024
    const int MLDS = 140 * 256;        // 35840 B
    unsigned char* wpl[4] = {wpf8, wpf8 + SZF8_, wpf8 + 2 * (size_t)SZF8_,
                             wpf8 + 3 * (size_t)SZF8_};
    conv_mid<false><<<NBLK, 256, MLDS, stream>>>(H0, wpl[0], bias[1], H1,
                                                 nullptr, nullptr);
    conv_mid<false><<<NBLK, 256, MLDS, stream>>>(H1, wpl[1], bias[2], H0,
                                                 nullptr, nullptr);
    conv_mid<false><<<NBLK, 256, MLDS, stream>>>(H0, wpl[2], bias[3], H1,
                                                 nullptr, nullptr);
    conv_mid<true><<<NBLK, 256, MLDS, stream>>>(H1, wpl[3], bias[4], nullptr,
                                                w_out, em);

    crf_seg_kernel<<<B_ * SEG_ / 4, 256, 0, stream>>>(em, tr, b_out, segM);

    hipMemsetAsync(d_out, 0, sizeof(float), stream);
    crf_kernel<<<B_, 64, 0, stream>>>(em, segM, tags, st, et, tr, b_out,
                                      (float*)d_out);
}